// Round 3
// baseline (4191.039 us; speedup 1.0000x reference)
//
#include <hip/hip_runtime.h>
#include <hip/hip_bf16.h>
#include <math.h>

typedef short bf16x8 __attribute__((ext_vector_type(8)));
typedef float f32x16 __attribute__((ext_vector_type(16)));

#define DH 100      // hidden dim
#define SPB 20      // samples per block -> 2020 rows, padded to 2048
#define NCH 16      // chunks of 128 rows
#define WSTR 136    // LDS row stride in bf16 elems (272 B)

// ws float offsets
#define WS_CCW   0
#define WS_XSC   128
#define WS_OH0   256
#define WS_EOH1  260
#define WS_X2    272

__device__ __forceinline__ unsigned short f2bf(float f) {
    unsigned int u = __float_as_uint(f);
    unsigned int r = (u + 0x7FFFu + ((u >> 16) & 1u)) >> 16;  // RNE
    return (unsigned short)r;
}
__device__ __forceinline__ unsigned int pk2(float a, float b) {
    // packed f32->bf16 (v_cvt_pk_bf16_f32 on gfx950); low u16 = a
    __hip_bfloat162 h = __float22bfloat162_rn(make_float2(a, b));
    union { __hip_bfloat162 h; unsigned int u; } c; c.h = h; return c.u;
}

__global__ void setup_kernel(const float* __restrict__ logits,
                             const float* __restrict__ hb0,
                             const float* __restrict__ hW1,
                             const float* __restrict__ hb1,
                             const float* __restrict__ hW2,
                             const float* __restrict__ hb2,
                             const float* __restrict__ hW3,
                             const float* __restrict__ hb3,
                             float* __restrict__ ws,
                             float* __restrict__ out2, int n)
{
    int t = threadIdx.x;
    for (int i = blockIdx.x * blockDim.x + t; i < n; i += gridDim.x * blockDim.x)
        out2[i] = logits[i];
    if (blockIdx.x != 0) return;

    if (t < 128) {
        double ccw = 0.0, xs = 0.0;
        if (t <= 100) {
            double s = (double)t;
            for (int j = 0; j <= 100; j += 2) {
                double wj = (j == 0) ? 1.0 : 2.0 / (1.0 - (double)j * (double)j);
                double lam;
                if (t == 0) lam = 0.5;
                else {
                    lam = cos((double)j * s * M_PI / 100.0);
                    if (t == 100) lam *= 0.5;
                }
                ccw += lam * 0.02 * wj;
            }
            xs = (cos(s * M_PI / 100.0) + 1.0) * 0.5;
        }
        ws[WS_CCW + t] = (float)ccw;
        ws[WS_XSC + t] = (float)xs;
    }
    __syncthreads();

    __shared__ float bufA[DH], bufB[DH];
    for (int k = 0; k < 3; ++k) {
        if (t < DH) bufA[t] = fmaxf(hb0[k * DH + t], 0.f);
        __syncthreads();
        if (t < DH) {
            float acc = hb1[k * DH + t];
            const float* w = hW1 + (size_t)(k * DH + t) * DH;
            for (int i = 0; i < DH; ++i) acc = fmaf(w[i], bufA[i], acc);
            bufB[t] = fmaxf(acc, 0.f);
        }
        __syncthreads();
        if (t < DH) {
            float acc = hb2[k * DH + t];
            const float* w = hW2 + (size_t)(k * DH + t) * DH;
            for (int i = 0; i < DH; ++i) acc = fmaf(w[i], bufB[i], acc);
            bufA[t] = fmaxf(acc, 0.f);
        }
        __syncthreads();
        if (t < 2) {
            float acc = hb3[k * 2 + t];
            const float* w = hW3 + (size_t)(k * 2 + t) * DH;
            for (int i = 0; i < DH; ++i) acc = fmaf(w[i], bufA[i], acc);
            if (t == 0) ws[WS_OH0 + k] = acc;
            else        ws[WS_EOH1 + k] = expf(acc);
        }
        __syncthreads();
    }
}

// Transposed dataflow: C1 = W1·A1^T, C2 = W2·A2^T. The producing MFMA's
// C-layout (lane->sample-col m, regs->neuron rows) feeds the next layer's
// B-operand via a lane^32 shuffle exchange -- no LDS transpose, no barriers
// in the chunk loop. Biases ride in padded K-slot 100 (activation == 1.0).
__global__ __launch_bounds__(256, 2)
void mono_mfma(const float* __restrict__ xsrc,
               const float* __restrict__ iW0, const float* __restrict__ ib0,
               const float* __restrict__ iW1, const float* __restrict__ ib1,
               const float* __restrict__ iW2, const float* __restrict__ ib2,
               const float* __restrict__ iW3, const float* __restrict__ ib3,
               const float* __restrict__ ws,
               float* __restrict__ dst0, float* __restrict__ dst1,
               int kbase, int nTot)
{
    __shared__ __align__(16) unsigned short W1s[128 * WSTR];  // row n1, col kin; col 100 = b1
    __shared__ __align__(16) unsigned short W2s[128 * WSTR];  // row n2, col n1;  col 100 = b2
    __shared__ unsigned int wb_s[128];    // packed (bf16(b0)<<16)|bf16(w0); slot 100 = (1.0, 0)
    __shared__ unsigned int w3p_s[64];    // packed bf16 w3 pairs, indexed [hf][nt2][q][pr]
    __shared__ float xsc_s[128], ccw_s[128];
    __shared__ float xs_s[32], zs[32];

    const int tid = threadIdx.x;
    const int lane = tid & 63;
    const int wv = tid >> 6;
    const int hf = lane >> 5;
    const bool hfb = (hf != 0);
    const int l31 = lane & 31;
    const int k = kbase + blockIdx.y;
    float* __restrict__ dst = (blockIdx.y == 0) ? dst0 : dst1;

    const float* W1g = iW1 + (size_t)k * DH * DH;
    const float* W2g = iW2 + (size_t)k * DH * DH;

    if (tid < 128) {
        xsc_s[tid] = ws[WS_XSC + tid];
        ccw_s[tid] = ws[WS_CCW + tid];
        float w0 = (tid < DH) ? iW0[(k * DH + tid) * 3] : 0.f;   // h==0: feature 0 only
        float b0 = (tid < DH) ? ib0[k * DH + tid] : ((tid == DH) ? 1.f : 0.f);
        wb_s[tid] = ((unsigned int)f2bf(b0) << 16) | (unsigned int)f2bf(w0);
    }
    if (tid < 64) {
        int hf_i = tid >> 5, rem = tid & 31;
        int nt2 = rem >> 3, qq = (rem >> 1) & 3, pr = rem & 1;
        int n2e = 32 * nt2 + 8 * qq + 2 * pr + 4 * hf_i;
        float we = (n2e < DH) ? iW3[k * DH + n2e] : 0.f;
        float wo = (n2e + 1 < DH) ? iW3[k * DH + n2e + 1] : 0.f;
        w3p_s[tid] = ((unsigned int)f2bf(wo) << 16) | (unsigned int)f2bf(we);
    }
    if (tid < 32) {
        int n = blockIdx.x * SPB + tid;
        xs_s[tid] = (tid < SPB && n < nTot) ? xsrc[n] : 0.f;
        zs[tid] = 0.f;
    }
    for (int i = tid; i < 128 * 128; i += 256) {
        int r = i >> 7, c = i & 127;
        float v1 = 0.f, v2 = 0.f;
        if (r < DH) {
            if (c < DH)      { v1 = W1g[r * DH + c]; v2 = W2g[r * DH + c]; }
            else if (c == DH){ v1 = ib1[k * DH + r]; v2 = ib2[k * DH + r]; }
        }
        W1s[r * WSTR + c] = f2bf(v1);
        W2s[r * WSTR + c] = f2bf(v2);
    }
    __syncthreads();

    unsigned int w3r[32];
    #pragma unroll
    for (int j = 0; j < 32; ++j) w3r[j] = w3p_s[hf * 32 + j];
    const float b3 = ib3[k];
    const float e1 = ws[WS_EOH1 + k];
    const float o0 = ws[WS_OH0 + k];
    const unsigned int bias1 = hfb ? 0u : 0x00003F80u;  // bf16(1.0) at k=100 slot

    union FR { bf16x8 v; unsigned int u32[4]; };

    for (int ch = 0; ch < NCH; ++ch) {
        const int mrow = ch * 128 + wv * 32 + l31;
        const int nloc = (mrow * 649) >> 16;   // mrow / 101
        const int p = mrow - nloc * 101;
        const float u = xs_s[nloc] * xsc_s[p];

        // ---- layer 1: B-frags for C1 = W1·A1^T built in registers ----
        FR a1[8];
        #pragma unroll
        for (int ks = 0; ks < 8; ++ks) {
            const unsigned int* wb = &wb_s[ks * 16 + hf * 8];
            uint4 qa = *(const uint4*)wb;
            uint4 qb = *(const uint4*)(wb + 4);
            unsigned int q[8] = {qa.x, qa.y, qa.z, qa.w, qb.x, qb.y, qb.z, qb.w};
            float v[8];
            #pragma unroll
            for (int j = 0; j < 8; ++j) {
                float w0 = __uint_as_float(q[j] << 16);
                float b0 = __uint_as_float(q[j] & 0xFFFF0000u);
                v[j] = fmaxf(fmaf(u, w0, b0), 0.f);
            }
            a1[ks].u32[0] = pk2(v[0], v[1]);
            a1[ks].u32[1] = pk2(v[2], v[3]);
            a1[ks].u32[2] = pk2(v[4], v[5]);
            a1[ks].u32[3] = pk2(v[6], v[7]);
        }

        // ---- layer 2 transposed: C1[n1][m], nt1 pairs; exchange -> f3 B-frags ----
        FR f3[8];
        #pragma unroll
        for (int np = 0; np < 2; ++np) {
            f32x16 acA, acB;
            #pragma unroll
            for (int r = 0; r < 16; ++r) { acA[r] = 0.f; acB[r] = 0.f; }
            #pragma unroll
            for (int ks = 0; ks < 8; ++ks) {
                bf16x8 wA = *(const bf16x8*)&W1s[((np * 2) * 32 + l31) * WSTR + ks * 16 + hf * 8];
                bf16x8 wB = *(const bf16x8*)&W1s[((np * 2 + 1) * 32 + l31) * WSTR + ks * 16 + hf * 8];
                acA = __builtin_amdgcn_mfma_f32_32x32x16_bf16(wA, a1[ks].v, acA, 0, 0, 0);
                acB = __builtin_amdgcn_mfma_f32_32x32x16_bf16(wB, a1[ks].v, acB, 0, 0, 0);
            }
            #pragma unroll
            for (int half = 0; half < 2; ++half) {
                const f32x16& ac = half ? acB : acA;
                unsigned int pk[4][2];
                #pragma unroll
                for (int qi = 0; qi < 4; ++qi) {
                    float a0 = fmaxf(ac[4 * qi + 0], 0.f);
                    float a1v = fmaxf(ac[4 * qi + 1], 0.f);
                    float a2 = fmaxf(ac[4 * qi + 2], 0.f);
                    float a3 = fmaxf(ac[4 * qi + 3], 0.f);
                    pk[qi][0] = pk2(a0, a1v);
                    pk[qi][1] = pk2(a2, a3);
                }
                int fb = (np * 2 + half) * 2;   // this nt1 covers ks = fb, fb+1
                #pragma unroll
                for (int kk = 0; kk < 2; ++kk) {
                    // send partner what it needs (its q = 2kk + partner_hf), keep own
                    unsigned int X0 = hfb ? pk[2 * kk][0] : pk[2 * kk + 1][0];
                    unsigned int X1 = hfb ? pk[2 * kk][1] : pk[2 * kk + 1][1];
                    unsigned int O0 = hfb ? pk[2 * kk + 1][0] : pk[2 * kk][0];
                    unsigned int O1 = hfb ? pk[2 * kk + 1][1] : pk[2 * kk][1];
                    unsigned int Y0 = (unsigned int)__shfl_xor((int)X0, 32, 64);
                    unsigned int Y1 = (unsigned int)__shfl_xor((int)X1, 32, 64);
                    // u32[0,1] <- source half 0 ; u32[2,3] <- source half 1
                    f3[fb + kk].u32[0] = hfb ? Y0 : O0;
                    f3[fb + kk].u32[1] = hfb ? Y1 : O1;
                    f3[fb + kk].u32[2] = hfb ? O0 : Y0;
                    f3[fb + kk].u32[3] = hfb ? O1 : Y1;
                }
            }
        }
        f3[6].u32[2] |= bias1;   // A2 slot n1=100 := 1.0 (hf=0 lanes, j=4 low half)

        // ---- layer 3 transposed: C2[n2][m] + w3-weighted register reduction ----
        float oacc = 0.f;
        #pragma unroll
        for (int np = 0; np < 2; ++np) {
            f32x16 acA, acB;
            #pragma unroll
            for (int r = 0; r < 16; ++r) { acA[r] = 0.f; acB[r] = 0.f; }
            #pragma unroll
            for (int ks = 0; ks < 8; ++ks) {
                bf16x8 wA = *(const bf16x8*)&W2s[((np * 2) * 32 + l31) * WSTR + ks * 16 + hf * 8];
                bf16x8 wB = *(const bf16x8*)&W2s[((np * 2 + 1) * 32 + l31) * WSTR + ks * 16 + hf * 8];
                acA = __builtin_amdgcn_mfma_f32_32x32x16_bf16(wA, f3[ks].v, acA, 0, 0, 0);
                acB = __builtin_amdgcn_mfma_f32_32x32x16_bf16(wB, f3[ks].v, acB, 0, 0, 0);
            }
            #pragma unroll
            for (int half = 0; half < 2; ++half) {
                const f32x16& ac = half ? acB : acA;
                int nt2 = np * 2 + half;
                #pragma unroll
                for (int r = 0; r < 16; ++r) {
                    int qi = r >> 2, s = r & 3;
                    unsigned int wu = w3r[nt2 * 8 + qi * 2 + (s >> 1)];
                    float w3v = __uint_as_float((s & 1) ? (wu & 0xFFFF0000u) : (wu << 16));
                    oacc = fmaf(fmaxf(ac[r], 0.f), w3v, oacc);
                }
            }
        }
        float o = oacc + __shfl_xor(oacc, 32, 64) + b3;
        if (!hfb) {
            float dz = (o > 0.f) ? (o + 1.f) : expf(o);   // elu(o) + 1
            atomicAdd(&zs[nloc], dz * ccw_s[p]);
        }
    }

    __syncthreads();
    if (tid < SPB) {
        int n = blockIdx.x * SPB + tid;
        if (n < nTot) dst[n] = fmaf(e1, 0.5f * xs_s[tid] * zs[tid], o0);
    }
}

extern "C" void kernel_launch(void* const* d_in, const int* in_sizes, int n_in,
                              void* d_out, int out_size, void* d_ws, size_t ws_size,
                              hipStream_t stream)
{
    const float* logits = (const float*)d_in[0];
    const float* iW0 = (const float*)d_in[2];
    const float* ib0 = (const float*)d_in[3];
    const float* iW1 = (const float*)d_in[4];
    const float* ib1 = (const float*)d_in[5];
    const float* iW2 = (const float*)d_in[6];
    const float* ib2 = (const float*)d_in[7];
    const float* iW3 = (const float*)d_in[8];
    const float* ib3 = (const float*)d_in[9];
    const float* hb0 = (const float*)d_in[11];
    const float* hW1 = (const float*)d_in[12];
    const float* hb1 = (const float*)d_in[13];
    const float* hW2 = (const float*)d_in[14];
    const float* hb2 = (const float*)d_in[15];
    const float* hW3 = (const float*)d_in[16];
    const float* hb3 = (const float*)d_in[17];
    float* out = (float*)d_out;
    float* ws = (float*)d_ws;
    int n = in_sizes[0];
    int nblocks = (n + SPB - 1) / SPB;

    hipLaunchKernelGGL(setup_kernel, dim3(64), dim3(256), 0, stream,
                       logits, hb0, hW1, hb1, hW2, hb2, hW3, hb3, ws, out + 2 * n, n);
    // phase A: k=0 -> x2 (workspace), k=1 -> y1
    hipLaunchKernelGGL(mono_mfma, dim3(nblocks, 2), dim3(256), 0, stream,
                       logits, iW0, ib0, iW1, ib1, iW2, ib2, iW3, ib3, ws,
                       ws + WS_X2, out, 0, n);
    // phase B: k=2 on x2 -> y2
    hipLaunchKernelGGL(mono_mfma, dim3(nblocks, 1), dim3(256), 0, stream,
                       ws + WS_X2, iW0, ib0, iW1, ib1, iW2, ib2, iW3, ib3, ws,
                       out + n, out + n, 2, n);
}

// Round 4
// 1378.349 us; speedup vs baseline: 3.0406x; 3.0406x over previous
//
#include <hip/hip_runtime.h>
#include <hip/hip_bf16.h>
#include <math.h>

typedef short bf16x8 __attribute__((ext_vector_type(8)));
typedef float f32x16 __attribute__((ext_vector_type(16)));

#define DH 100      // hidden dim
#define SPB 20      // samples per block -> 2020 rows, padded to 2048
#define NCH 16      // chunks of 128 rows
#define WSTR 136    // LDS row stride in bf16 elems (272 B, 16B-aligned, b128-clean)

// ws float offsets
#define WS_CCW   0
#define WS_XSC   128
#define WS_OH0   256
#define WS_EOH1  260
#define WS_X2    272

__device__ __forceinline__ unsigned short f2bf(float f) {
    unsigned int u = __float_as_uint(f);
    unsigned int r = (u + 0x7FFFu + ((u >> 16) & 1u)) >> 16;  // RNE
    return (unsigned short)r;
}
__device__ __forceinline__ unsigned int pk2(float a, float b) {
    // packed f32->bf16 (v_cvt_pk_bf16_f32); low u16 = a
    __hip_bfloat162 h = __float22bfloat162_rn(make_float2(a, b));
    union { __hip_bfloat162 h; unsigned int u; } c; c.h = h; return c.u;
}

__global__ void setup_kernel(const float* __restrict__ logits,
                             const float* __restrict__ hb0,
                             const float* __restrict__ hW1,
                             const float* __restrict__ hb1,
                             const float* __restrict__ hW2,
                             const float* __restrict__ hb2,
                             const float* __restrict__ hW3,
                             const float* __restrict__ hb3,
                             float* __restrict__ ws,
                             float* __restrict__ out2, int n)
{
    int t = threadIdx.x;
    for (int i = blockIdx.x * blockDim.x + t; i < n; i += gridDim.x * blockDim.x)
        out2[i] = logits[i];
    if (blockIdx.x != 0) return;

    if (t < 128) {
        double ccw = 0.0, xs = 0.0;
        if (t <= 100) {
            double s = (double)t;
            for (int j = 0; j <= 100; j += 2) {
                double wj = (j == 0) ? 1.0 : 2.0 / (1.0 - (double)j * (double)j);
                double lam;
                if (t == 0) lam = 0.5;
                else {
                    lam = cos((double)j * s * M_PI / 100.0);
                    if (t == 100) lam *= 0.5;
                }
                ccw += lam * 0.02 * wj;
            }
            xs = (cos(s * M_PI / 100.0) + 1.0) * 0.5;
        }
        ws[WS_CCW + t] = (float)ccw;
        ws[WS_XSC + t] = (float)xs;
    }
    __syncthreads();

    __shared__ float bufA[DH], bufB[DH];
    for (int k = 0; k < 3; ++k) {
        if (t < DH) bufA[t] = fmaxf(hb0[k * DH + t], 0.f);
        __syncthreads();
        if (t < DH) {
            float acc = hb1[k * DH + t];
            const float* w = hW1 + (size_t)(k * DH + t) * DH;
            for (int i = 0; i < DH; ++i) acc = fmaf(w[i], bufA[i], acc);
            bufB[t] = fmaxf(acc, 0.f);
        }
        __syncthreads();
        if (t < DH) {
            float acc = hb2[k * DH + t];
            const float* w = hW2 + (size_t)(k * DH + t) * DH;
            for (int i = 0; i < DH; ++i) acc = fmaf(w[i], bufB[i], acc);
            bufA[t] = fmaxf(acc, 0.f);
        }
        __syncthreads();
        if (t < 2) {
            float acc = hb3[k * 2 + t];
            const float* w = hW3 + (size_t)(k * 2 + t) * DH;
            for (int i = 0; i < DH; ++i) acc = fmaf(w[i], bufA[i], acc);
            if (t == 0) ws[WS_OH0 + k] = acc;
            else        ws[WS_EOH1 + k] = expf(acc);
        }
        __syncthreads();
    }
}

// Transposed dataflow (R3, verified): C1 = W1·A1^T, C2 = W2·A2^T; inter-layer
// C->B-operand transform via lane^32 shuffle exchange, no LDS round-trip and
// no barriers in the chunk loop. ks-outer loops keep register pressure ~160.
__global__ __launch_bounds__(256, 1)
void mono_mfma(const float* __restrict__ xsrc,
               const float* __restrict__ iW0, const float* __restrict__ ib0,
               const float* __restrict__ iW1, const float* __restrict__ ib1,
               const float* __restrict__ iW2, const float* __restrict__ ib2,
               const float* __restrict__ iW3, const float* __restrict__ ib3,
               const float* __restrict__ ws,
               float* __restrict__ dst0, float* __restrict__ dst1,
               int kbase, int nTot)
{
    __shared__ __align__(16) unsigned short W1s[128 * WSTR];  // row n1, col kin; col 100 = b1
    __shared__ __align__(16) unsigned short W2s[128 * WSTR];  // row n2, col n1;  col 100 = b2
    __shared__ unsigned int wb_s[128];    // packed (bf16(b0)<<16)|bf16(w0); slot 100 = (1.0, 0)
    __shared__ unsigned int w3p_s[64];    // packed bf16 w3 pairs, indexed [hf][nt2][q][pr]
    __shared__ float xsc_s[128], ccw_s[128];
    __shared__ float xs_s[32], zs[32];

    const int tid = threadIdx.x;
    const int lane = tid & 63;
    const int wv = tid >> 6;
    const int hf = lane >> 5;
    const bool hfb = (hf != 0);
    const int l31 = lane & 31;
    const int k = kbase + blockIdx.y;
    float* __restrict__ dst = (blockIdx.y == 0) ? dst0 : dst1;

    const float* W1g = iW1 + (size_t)k * DH * DH;
    const float* W2g = iW2 + (size_t)k * DH * DH;

    if (tid < 128) {
        xsc_s[tid] = ws[WS_XSC + tid];
        ccw_s[tid] = ws[WS_CCW + tid];
        float w0 = (tid < DH) ? iW0[(k * DH + tid) * 3] : 0.f;   // h==0: feature 0 only
        float b0 = (tid < DH) ? ib0[k * DH + tid] : ((tid == DH) ? 1.f : 0.f);
        wb_s[tid] = ((unsigned int)f2bf(b0) << 16) | (unsigned int)f2bf(w0);
    }
    if (tid < 64) {
        int hf_i = tid >> 5, rem = tid & 31;
        int nt2 = rem >> 3, qq = (rem >> 1) & 3, pr = rem & 1;
        int n2e = 32 * nt2 + 8 * qq + 2 * pr + 4 * hf_i;
        float we = (n2e < DH) ? iW3[k * DH + n2e] : 0.f;
        float wo = (n2e + 1 < DH) ? iW3[k * DH + n2e + 1] : 0.f;
        w3p_s[tid] = ((unsigned int)f2bf(wo) << 16) | (unsigned int)f2bf(we);
    }
    if (tid < 32) {
        int n = blockIdx.x * SPB + tid;
        xs_s[tid] = (tid < SPB && n < nTot) ? xsrc[n] : 0.f;
        zs[tid] = 0.f;
    }
    for (int i = tid; i < 128 * 128; i += 256) {
        int r = i >> 7, c = i & 127;
        float v1 = 0.f, v2 = 0.f;
        if (r < DH) {
            if (c < DH)      { v1 = W1g[r * DH + c]; v2 = W2g[r * DH + c]; }
            else if (c == DH){ v1 = ib1[k * DH + r]; v2 = ib2[k * DH + r]; }
        }
        W1s[r * WSTR + c] = f2bf(v1);
        W2s[r * WSTR + c] = f2bf(v2);
    }
    __syncthreads();

    unsigned int w3r[32];
    #pragma unroll
    for (int j = 0; j < 32; ++j) w3r[j] = w3p_s[hf * 32 + j];
    const float b3 = ib3[k];
    const float e1 = ws[WS_EOH1 + k];
    const float o0 = ws[WS_OH0 + k];
    const unsigned int bias1 = hfb ? 0u : 0x00003F80u;  // bf16(1.0) at n1=100 slot

    union FR { bf16x8 v; unsigned int u32[4]; };

    for (int ch = 0; ch < NCH; ++ch) {
        const int mrow = ch * 128 + wv * 32 + l31;
        const int nloc = (mrow * 649) >> 16;   // mrow / 101
        const int p = mrow - nloc * 101;
        const float u = xs_s[nloc] * xsc_s[p];

        // ---- layer 2: C1 = W1·A1^T, ks-outer, 4 tile-accumulators ----
        f32x16 acc[4];
        #pragma unroll
        for (int nt = 0; nt < 4; ++nt)
            #pragma unroll
            for (int r = 0; r < 16; ++r) acc[nt][r] = 0.f;

        #pragma unroll
        for (int ks = 0; ks < 8; ++ks) {
            // build layer-1 B-frag for this ks (rank-1 in u; bias in slot 100)
            const unsigned int* wb = &wb_s[ks * 16 + hf * 8];
            uint4 qa = *(const uint4*)wb;
            uint4 qb = *(const uint4*)(wb + 4);
            unsigned int q[8] = {qa.x, qa.y, qa.z, qa.w, qb.x, qb.y, qb.z, qb.w};
            float v[8];
            #pragma unroll
            for (int j = 0; j < 8; ++j) {
                float w0 = __uint_as_float(q[j] << 16);
                float b0 = __uint_as_float(q[j] & 0xFFFF0000u);
                v[j] = fmaxf(fmaf(u, w0, b0), 0.f);
            }
            FR a1;
            a1.u32[0] = pk2(v[0], v[1]);
            a1.u32[1] = pk2(v[2], v[3]);
            a1.u32[2] = pk2(v[4], v[5]);
            a1.u32[3] = pk2(v[6], v[7]);
            #pragma unroll
            for (int nt = 0; nt < 4; ++nt) {
                bf16x8 wA = *(const bf16x8*)&W1s[(nt * 32 + l31) * WSTR + ks * 16 + hf * 8];
                acc[nt] = __builtin_amdgcn_mfma_f32_32x32x16_bf16(wA, a1.v, acc[nt], 0, 0, 0);
            }
        }

        // ---- C1 -> A2 B-frags via lane^32 exchange ----
        FR f3[8];
        #pragma unroll
        for (int nt = 0; nt < 4; ++nt) {
            unsigned int pk[4][2];
            #pragma unroll
            for (int qi = 0; qi < 4; ++qi) {
                float a0 = fmaxf(acc[nt][4 * qi + 0], 0.f);
                float a1v = fmaxf(acc[nt][4 * qi + 1], 0.f);
                float a2 = fmaxf(acc[nt][4 * qi + 2], 0.f);
                float a3 = fmaxf(acc[nt][4 * qi + 3], 0.f);
                pk[qi][0] = pk2(a0, a1v);
                pk[qi][1] = pk2(a2, a3);
            }
            #pragma unroll
            for (int kk = 0; kk < 2; ++kk) {
                unsigned int X0 = hfb ? pk[2 * kk][0] : pk[2 * kk + 1][0];
                unsigned int X1 = hfb ? pk[2 * kk][1] : pk[2 * kk + 1][1];
                unsigned int O0 = hfb ? pk[2 * kk + 1][0] : pk[2 * kk][0];
                unsigned int O1 = hfb ? pk[2 * kk + 1][1] : pk[2 * kk][1];
                unsigned int Y0 = (unsigned int)__shfl_xor((int)X0, 32, 64);
                unsigned int Y1 = (unsigned int)__shfl_xor((int)X1, 32, 64);
                f3[nt * 2 + kk].u32[0] = hfb ? Y0 : O0;
                f3[nt * 2 + kk].u32[1] = hfb ? Y1 : O1;
                f3[nt * 2 + kk].u32[2] = hfb ? O0 : Y0;
                f3[nt * 2 + kk].u32[3] = hfb ? O1 : Y1;
            }
        }
        f3[6].u32[2] |= bias1;   // A2 slot n1=100 := 1.0 (hf=0, low half)

        // ---- layer 3: C2 = W2·A2^T, ks-outer ----
        f32x16 acc2[4];
        #pragma unroll
        for (int nt = 0; nt < 4; ++nt)
            #pragma unroll
            for (int r = 0; r < 16; ++r) acc2[nt][r] = 0.f;
        #pragma unroll
        for (int ks = 0; ks < 8; ++ks) {
            #pragma unroll
            for (int nt = 0; nt < 4; ++nt) {
                bf16x8 wA = *(const bf16x8*)&W2s[(nt * 32 + l31) * WSTR + ks * 16 + hf * 8];
                acc2[nt] = __builtin_amdgcn_mfma_f32_32x32x16_bf16(wA, f3[ks].v, acc2[nt], 0, 0, 0);
            }
        }

        // ---- epilogue: o = sum relu(C2)·w3; elu+1; segmented butterfly; 1-2 atomics ----
        float oacc = 0.f;
        #pragma unroll
        for (int nt2 = 0; nt2 < 4; ++nt2) {
            #pragma unroll
            for (int r = 0; r < 16; ++r) {
                int qi = r >> 2, s = r & 3;
                unsigned int wu = w3r[nt2 * 8 + qi * 2 + (s >> 1)];
                float w3v = __uint_as_float((s & 1) ? (wu & 0xFFFF0000u) : (wu << 16));
                oacc = fmaf(fmaxf(acc2[nt2][r], 0.f), w3v, oacc);
            }
        }
        float o = oacc + __shfl_xor(oacc, 32, 64) + b3;
        float dz = (o > 0.f) ? (o + 1.f) : expf(o);   // elu(o) + 1
        float val = dz * ccw_s[p];
        int nA = __shfl(nloc, 0, 32);
        int nB = __shfl(nloc, 31, 32);
        float vA = (nloc == nA) ? val : 0.f;
        vA += __shfl_xor(vA, 16, 32);
        vA += __shfl_xor(vA, 8, 32);
        vA += __shfl_xor(vA, 4, 32);
        vA += __shfl_xor(vA, 2, 32);
        vA += __shfl_xor(vA, 1, 32);
        if (lane == 0) atomicAdd(&zs[nA], vA);
        if (nB != nA) {
            float vB = (nloc == nB) ? val : 0.f;
            vB += __shfl_xor(vB, 16, 32);
            vB += __shfl_xor(vB, 8, 32);
            vB += __shfl_xor(vB, 4, 32);
            vB += __shfl_xor(vB, 2, 32);
            vB += __shfl_xor(vB, 1, 32);
            if (lane == 1) atomicAdd(&zs[nB], vB);
        }
    }

    __syncthreads();
    if (tid < SPB) {
        int n = blockIdx.x * SPB + tid;
        if (n < nTot) dst[n] = fmaf(e1, 0.5f * xs_s[tid] * zs[tid], o0);
    }
}

extern "C" void kernel_launch(void* const* d_in, const int* in_sizes, int n_in,
                              void* d_out, int out_size, void* d_ws, size_t ws_size,
                              hipStream_t stream)
{
    const float* logits = (const float*)d_in[0];
    const float* iW0 = (const float*)d_in[2];
    const float* ib0 = (const float*)d_in[3];
    const float* iW1 = (const float*)d_in[4];
    const float* ib1 = (const float*)d_in[5];
    const float* iW2 = (const float*)d_in[6];
    const float* ib2 = (const float*)d_in[7];
    const float* iW3 = (const float*)d_in[8];
    const float* ib3 = (const float*)d_in[9];
    const float* hb0 = (const float*)d_in[11];
    const float* hW1 = (const float*)d_in[12];
    const float* hb1 = (const float*)d_in[13];
    const float* hW2 = (const float*)d_in[14];
    const float* hb2 = (const float*)d_in[15];
    const float* hW3 = (const float*)d_in[16];
    const float* hb3 = (const float*)d_in[17];
    float* out = (float*)d_out;
    float* ws = (float*)d_ws;
    int n = in_sizes[0];
    int nblocks = (n + SPB - 1) / SPB;

    hipLaunchKernelGGL(setup_kernel, dim3(64), dim3(256), 0, stream,
                       logits, hb0, hW1, hb1, hW2, hb2, hW3, hb3, ws, out + 2 * n, n);
    // phase A: k=0 -> x2 (workspace), k=1 -> y1
    hipLaunchKernelGGL(mono_mfma, dim3(nblocks, 2), dim3(256), 0, stream,
                       logits, iW0, ib0, iW1, ib1, iW2, ib2, iW3, ib3, ws,
                       ws + WS_X2, out, 0, n);
    // phase B: k=2 on x2 -> y2
    hipLaunchKernelGGL(mono_mfma, dim3(nblocks, 1), dim3(256), 0, stream,
                       ws + WS_X2, iW0, ib0, iW1, ib1, iW2, ib2, iW3, ib3, ws,
                       out + n, out + n, 2, n);
}